// Round 16
// baseline (1524.160 us; speedup 1.0000x reference)
//
#include <hip/hip_runtime.h>
#include <hip/hip_bf16.h>
#include <hip/hip_cooperative_groups.h>
#include <math.h>

namespace cg = cooperative_groups;

#define N_NODES 40000
#define NE      640000
#define FIN     33
#define H       128
#define COUT    3
#define NLAYERS 8
#define ALPHA   0.1f
#define THETA   0.5f
#define CAP     96             // max bucket capacity; deg ~ Poisson(16), P(>96) ~ 1e-40

// setup mega-kernel block ranges
#define SB_SCAT 625            // scatter: 625 blocks * 256 thr * 4 edges = 640000
#define SB_WPRE 512            // wprep:   512 blocks * 256 = 131072 elements
#define SB_XIN  2500           // xin:     2500 blocks * 16 nodes = 40000

// persistent cooperative kernel: conservative co-residency (2 blocks/CU)
#define PBLK    512
#define NWAVE   (PBLK * 4)     // 2048 waves
#define NTILE   (N_NODES / 16) // 2500 gemm tiles of 16 rows

typedef __bf16 bf16x8 __attribute__((ext_vector_type(8)));
typedef float  f32x4  __attribute__((ext_vector_type(4)));

__device__ inline unsigned short f2bf(float f) {
    __hip_bfloat16 b = __float2bfloat16(f);
    return *(unsigned short*)&b;
}
__device__ inline float bf2f(unsigned short u) {
    __hip_bfloat16 b = *(__hip_bfloat16*)&u;
    return __bfloat162float(b);
}

// ---- setup mega-kernel: [scatter | wprep(W'-fold) | xin] by block range ----
__global__ __launch_bounds__(256) void k_setup(
        const int* __restrict__ row, const int* __restrict__ col,
        const float* __restrict__ w, int* __restrict__ cnt,
        unsigned int* __restrict__ bucket,
        const float* __restrict__ Wconv, unsigned short* __restrict__ Wtbf,
        const float* __restrict__ x, const float* __restrict__ Win,
        const float* __restrict__ bin,
        unsigned short* __restrict__ x0bf, unsigned short* __restrict__ hbf) {
    __shared__ float sW[H * FIN];
    __shared__ float sx[16][FIN];
    int b = blockIdx.x, t = threadIdx.x;

    if (b < SB_SCAT) {
        int e0 = (b * 256 + t) * 4;
        int r[4], pos[4];
        unsigned int rec[4];
        #pragma unroll
        for (int i = 0; i < 4; i++) {
            int e = e0 + i;
            r[i] = row[e];
            unsigned int wb = f2bf((1.0f - ALPHA) * w[e]);
            rec[i] = (wb << 16) | (unsigned int)col[e];
        }
        #pragma unroll
        for (int i = 0; i < 4; i++) pos[i] = atomicAdd(&cnt[r[i]], 1);
        #pragma unroll
        for (int i = 0; i < 4; i++) bucket[(size_t)r[i] * CAP + pos[i]] = rec[i];
        return;
    }
    if (b < SB_SCAT + SB_WPRE) {
        // W' = (1-beta)*I + beta*W, transposed to [l][j][k], bf16
        int idx = (b - SB_SCAT) * 256 + t;        // = l*16384 + k*128 + j
        int l = idx >> 14;
        int rem = idx & 16383;
        int k = rem >> 7, j = rem & 127;
        float beta = logf(THETA / (float)(l + 1) + 1.0f);
        float v = beta * Wconv[idx];
        if (j == k) v += 1.0f - beta;
        Wtbf[l * 16384 + j * 128 + k] = f2bf(v);
        return;
    }
    {
        // x0 = relu(x @ W_in^T + b_in); x0bf, hbf = bf16(x0)
        int n0 = (b - SB_SCAT - SB_WPRE) * 16;
        for (int i = t; i < H * FIN; i += 256) sW[i] = Win[i];
        for (int i = t; i < 16 * FIN; i += 256)
            sx[i / FIN][i % FIN] = x[(size_t)(n0 + i / FIN) * FIN + (i % FIN)];
        __syncthreads();
        int f = t % H;
        int l0 = t / H;
        float bv = bin[f];
        for (int lo = l0; lo < 16; lo += 2) {
            float acc = bv;
            #pragma unroll
            for (int k = 0; k < FIN; k++) acc += sx[lo][k] * sW[f * FIN + k];
            acc = fmaxf(acc, 0.f);
            size_t idx = (size_t)(n0 + lo) * H + f;
            unsigned short bb = f2bf(acc);
            x0bf[idx] = bb;
            hbf[idx] = bb;
        }
    }
}

// ---- gemm tile helper (one 16-row tile, one wave) -------------------------
__device__ inline void gemm_tile(int rbase, int quad, int l16,
        const unsigned short* __restrict__ xxbf, const unsigned short* __restrict__ Wl,
        unsigned short* __restrict__ hbf, float (&h)[8][4], bool last,
        const float* __restrict__ Wout, const float* __restrict__ bout,
        float* __restrict__ out) {
    f32x4 acc[8];
    #pragma unroll
    for (int j = 0; j < 8; j++) acc[j] = (f32x4){0.f, 0.f, 0.f, 0.f};
    #pragma unroll
    for (int k0 = 0; k0 < 4; k0++) {
        bf16x8 av = *(const bf16x8*)(xxbf + (size_t)(rbase + l16) * H + k0 * 32 + quad * 8);
        #pragma unroll
        for (int j = 0; j < 8; j++) {
            bf16x8 bv = *(const bf16x8*)(Wl + (size_t)(j * 16 + l16) * H + k0 * 32 + quad * 8);
            acc[j] = __builtin_amdgcn_mfma_f32_16x16x32_bf16(av, bv, acc[j], 0, 0, 0);
        }
    }
    if (!last) {
        #pragma unroll
        for (int j = 0; j < 8; j++) {
            int col = j * 16 + l16;
            #pragma unroll
            for (int r = 0; r < 4; r++) {
                h[j][r] += fmaxf(acc[j][r], 0.f);
                hbf[(size_t)(rbase + quad * 4 + r) * H + col] = f2bf(h[j][r]);
            }
        }
    } else {
        float po[4][3];
        #pragma unroll
        for (int r = 0; r < 4; r++) { po[r][0] = 0.f; po[r][1] = 0.f; po[r][2] = 0.f; }
        #pragma unroll
        for (int j = 0; j < 8; j++) {
            int col = j * 16 + l16;
            float w0 = Wout[col], w1 = Wout[H + col], w2 = Wout[2 * H + col];
            #pragma unroll
            for (int r = 0; r < 4; r++) {
                float hv = h[j][r] + fmaxf(acc[j][r], 0.f);
                po[r][0] += hv * w0; po[r][1] += hv * w1; po[r][2] += hv * w2;
            }
        }
        #pragma unroll
        for (int off = 1; off < 16; off <<= 1) {
            #pragma unroll
            for (int r = 0; r < 4; r++) {
                po[r][0] += __shfl_xor(po[r][0], off);
                po[r][1] += __shfl_xor(po[r][1], off);
                po[r][2] += __shfl_xor(po[r][2], off);
            }
        }
        if (l16 == 0) {
            #pragma unroll
            for (int r = 0; r < 4; r++) {
                int row = rbase + quad * 4 + r;
                out[(size_t)row * 3 + 0] = po[r][0] + bout[0];
                out[(size_t)row * 3 + 1] = po[r][1] + bout[1];
                out[(size_t)row * 3 + 2] = po[r][2] + bout[2];
            }
        }
    }
}

// ---- persistent cooperative kernel: all 8 layers, grid.sync between phases.
// spmm: 2048 waves x ~20 rows (lane-group gathers). gemm: each wave owns up
// to TWO fixed 16-row tiles; h kept fp32 in registers across all layers.
__global__ __launch_bounds__(256, 2) void k_layers(
        const int* __restrict__ cnt, const unsigned int* __restrict__ bucket,
        const unsigned short* __restrict__ x0bf, unsigned short* __restrict__ hbf,
        unsigned short* __restrict__ xxbf, const unsigned short* __restrict__ Wtbf,
        const float* __restrict__ Wout, const float* __restrict__ bout,
        float* __restrict__ out) {
    cg::grid_group grid = cg::this_grid();
    int wave_g = (int)((blockIdx.x * 256 + threadIdx.x) >> 6);   // 0..2047
    int lane = threadIdx.x & 63;
    int slot = lane >> 4, fid = lane & 15;       // spmm roles
    int quad = lane >> 4, l16 = lane & 15;       // gemm roles

    int t0 = wave_g;                 // always < 2048 < NTILE
    int t1 = wave_g + NWAVE;         // valid if < NTILE (wave_g < 452)
    bool h1v = t1 < NTILE;
    int rb0 = t0 * 16, rb1 = t1 * 16;

    float h0[8][4], h1[8][4];
    #pragma unroll
    for (int j = 0; j < 8; j++)
        #pragma unroll
        for (int r = 0; r < 4; r++)
            h0[j][r] = bf2f(x0bf[(size_t)(rb0 + quad * 4 + r) * H + j * 16 + l16]);
    if (h1v) {
        #pragma unroll
        for (int j = 0; j < 8; j++)
            #pragma unroll
            for (int r = 0; r < 4; r++)
                h1[j][r] = bf2f(x0bf[(size_t)(rb1 + quad * 4 + r) * H + j * 16 + l16]);
    }

    for (int l = 0; l < NLAYERS; l++) {
        // ---------------- spmm phase ----------------
        for (int row = wave_g; row < N_NODES; row += NWAVE) {
            int deg = cnt[row];
            const unsigned int* ep = bucket + (size_t)row * CAP;
            float acc[8] = {0,0,0,0,0,0,0,0};
            for (int e = 0; e < deg; e += 16) {
                unsigned int u[4];
                uint4 q[4];
                #pragma unroll
                for (int k = 0; k < 4; k++) {
                    int ei = e + k * 4 + slot;
                    unsigned int uu = ep[ei];
                    u[k] = (ei < deg) ? uu : 0u;
                }
                #pragma unroll
                for (int k = 0; k < 4; k++)
                    q[k] = *(const uint4*)(hbf + (size_t)(u[k] & 0xffffu) * H + fid * 8);
                #pragma unroll
                for (int k = 0; k < 4; k++) {
                    float w = bf2f((unsigned short)(u[k] >> 16));
                    acc[0] += w * bf2f((unsigned short)(q[k].x & 0xffffu));
                    acc[1] += w * bf2f((unsigned short)(q[k].x >> 16));
                    acc[2] += w * bf2f((unsigned short)(q[k].y & 0xffffu));
                    acc[3] += w * bf2f((unsigned short)(q[k].y >> 16));
                    acc[4] += w * bf2f((unsigned short)(q[k].z & 0xffffu));
                    acc[5] += w * bf2f((unsigned short)(q[k].z >> 16));
                    acc[6] += w * bf2f((unsigned short)(q[k].w & 0xffffu));
                    acc[7] += w * bf2f((unsigned short)(q[k].w >> 16));
                }
            }
            #pragma unroll
            for (int j = 0; j < 8; j++) {
                acc[j] += __shfl_xor(acc[j], 16);
                acc[j] += __shfl_xor(acc[j], 32);
            }
            if (slot == 0) {
                uint4 xq = *(const uint4*)(x0bf + (size_t)row * H + fid * 8);
                float o0 = acc[0] + ALPHA * bf2f((unsigned short)(xq.x & 0xffffu));
                float o1 = acc[1] + ALPHA * bf2f((unsigned short)(xq.x >> 16));
                float o2 = acc[2] + ALPHA * bf2f((unsigned short)(xq.y & 0xffffu));
                float o3 = acc[3] + ALPHA * bf2f((unsigned short)(xq.y >> 16));
                float o4 = acc[4] + ALPHA * bf2f((unsigned short)(xq.z & 0xffffu));
                float o5 = acc[5] + ALPHA * bf2f((unsigned short)(xq.z >> 16));
                float o6 = acc[6] + ALPHA * bf2f((unsigned short)(xq.w & 0xffffu));
                float o7 = acc[7] + ALPHA * bf2f((unsigned short)(xq.w >> 16));
                uint4 rr;
                rr.x = (unsigned int)f2bf(o0) | ((unsigned int)f2bf(o1) << 16);
                rr.y = (unsigned int)f2bf(o2) | ((unsigned int)f2bf(o3) << 16);
                rr.z = (unsigned int)f2bf(o4) | ((unsigned int)f2bf(o5) << 16);
                rr.w = (unsigned int)f2bf(o6) | ((unsigned int)f2bf(o7) << 16);
                *(uint4*)(xxbf + (size_t)row * H + fid * 8) = rr;
            }
        }
        grid.sync();

        // ---------------- gemm phase ----------------
        const unsigned short* Wl = Wtbf + (size_t)l * H * H;
        bool last = (l == NLAYERS - 1);
        gemm_tile(rb0, quad, l16, xxbf, Wl, hbf, h0, last, Wout, bout, out);
        if (h1v)
            gemm_tile(rb1, quad, l16, xxbf, Wl, hbf, h1, last, Wout, bout, out);
        if (!last) grid.sync();
    }
}

// ---- fallback per-layer kernels (R14-proven) ------------------------------
__global__ __launch_bounds__(256) void k_spmm(const int* __restrict__ cnt,
                       const unsigned int* __restrict__ bucket,
                       const unsigned short* __restrict__ hbf,
                       const unsigned short* __restrict__ x0bf,
                       unsigned short* __restrict__ xxbf) {
    int wave = (blockIdx.x * blockDim.x + threadIdx.x) >> 6;
    int lane = threadIdx.x & 63;
    if (wave >= N_NODES) return;
    int deg = cnt[wave];
    const unsigned int* ep = bucket + (size_t)wave * CAP;
    int slot = lane >> 4, fid = lane & 15;
    float acc[8] = {0,0,0,0,0,0,0,0};
    for (int e = 0; e < deg; e += 16) {
        unsigned int u[4];
        uint4 q[4];
        #pragma unroll
        for (int k = 0; k < 4; k++) {
            int ei = e + k * 4 + slot;
            unsigned int uu = ep[ei];
            u[k] = (ei < deg) ? uu : 0u;
        }
        #pragma unroll
        for (int k = 0; k < 4; k++)
            q[k] = *(const uint4*)(hbf + (size_t)(u[k] & 0xffffu) * H + fid * 8);
        #pragma unroll
        for (int k = 0; k < 4; k++) {
            float w = bf2f((unsigned short)(u[k] >> 16));
            acc[0] += w * bf2f((unsigned short)(q[k].x & 0xffffu));
            acc[1] += w * bf2f((unsigned short)(q[k].x >> 16));
            acc[2] += w * bf2f((unsigned short)(q[k].y & 0xffffu));
            acc[3] += w * bf2f((unsigned short)(q[k].y >> 16));
            acc[4] += w * bf2f((unsigned short)(q[k].z & 0xffffu));
            acc[5] += w * bf2f((unsigned short)(q[k].z >> 16));
            acc[6] += w * bf2f((unsigned short)(q[k].w & 0xffffu));
            acc[7] += w * bf2f((unsigned short)(q[k].w >> 16));
        }
    }
    #pragma unroll
    for (int j = 0; j < 8; j++) {
        acc[j] += __shfl_xor(acc[j], 16);
        acc[j] += __shfl_xor(acc[j], 32);
    }
    if (slot == 0) {
        uint4 xq = *(const uint4*)(x0bf + (size_t)wave * H + fid * 8);
        float o0 = acc[0] + ALPHA * bf2f((unsigned short)(xq.x & 0xffffu));
        float o1 = acc[1] + ALPHA * bf2f((unsigned short)(xq.x >> 16));
        float o2 = acc[2] + ALPHA * bf2f((unsigned short)(xq.y & 0xffffu));
        float o3 = acc[3] + ALPHA * bf2f((unsigned short)(xq.y >> 16));
        float o4 = acc[4] + ALPHA * bf2f((unsigned short)(xq.z & 0xffffu));
        float o5 = acc[5] + ALPHA * bf2f((unsigned short)(xq.z >> 16));
        float o6 = acc[6] + ALPHA * bf2f((unsigned short)(xq.w & 0xffffu));
        float o7 = acc[7] + ALPHA * bf2f((unsigned short)(xq.w >> 16));
        uint4 r;
        r.x = (unsigned int)f2bf(o0) | ((unsigned int)f2bf(o1) << 16);
        r.y = (unsigned int)f2bf(o2) | ((unsigned int)f2bf(o3) << 16);
        r.z = (unsigned int)f2bf(o4) | ((unsigned int)f2bf(o5) << 16);
        r.w = (unsigned int)f2bf(o6) | ((unsigned int)f2bf(o7) << 16);
        *(uint4*)(xxbf + (size_t)wave * H + fid * 8) = r;
    }
}

__global__ __launch_bounds__(128) void k_gemm(const unsigned short* __restrict__ xxbf,
                       const unsigned short* __restrict__ Wtbf,
                       unsigned short* __restrict__ hbf,
                       const float* __restrict__ Wout, const float* __restrict__ bout,
                       float* __restrict__ out, int do_out) {
    int t = threadIdx.x;
    int wv = t >> 6, lane = t & 63;
    int quad = lane >> 4, l16 = lane & 15;
    int rbase = blockIdx.x * 32 + wv * 16;

    f32x4 acc[8];
    #pragma unroll
    for (int j = 0; j < 8; j++) acc[j] = (f32x4){0.f, 0.f, 0.f, 0.f};
    #pragma unroll
    for (int k0 = 0; k0 < 4; k0++) {
        bf16x8 av = *(const bf16x8*)(xxbf + (size_t)(rbase + l16) * H + k0 * 32 + quad * 8);
        #pragma unroll
        for (int j = 0; j < 8; j++) {
            bf16x8 bv = *(const bf16x8*)(Wtbf + (size_t)(j * 16 + l16) * H + k0 * 32 + quad * 8);
            acc[j] = __builtin_amdgcn_mfma_f32_16x16x32_bf16(av, bv, acc[j], 0, 0, 0);
        }
    }
    float po[4][3];
    #pragma unroll
    for (int r = 0; r < 4; r++) { po[r][0] = 0.f; po[r][1] = 0.f; po[r][2] = 0.f; }
    #pragma unroll
    for (int j = 0; j < 8; j++) {
        int col = j * 16 + l16;
        float w0 = 0.f, w1 = 0.f, w2 = 0.f;
        if (do_out) { w0 = Wout[col]; w1 = Wout[H + col]; w2 = Wout[2 * H + col]; }
        #pragma unroll
        for (int r = 0; r < 4; r++) {
            size_t idx = (size_t)(rbase + quad * 4 + r) * H + col;
            float hv = bf2f(hbf[idx]) + fmaxf(acc[j][r], 0.f);
            hbf[idx] = f2bf(hv);
            po[r][0] += hv * w0; po[r][1] += hv * w1; po[r][2] += hv * w2;
        }
    }
    if (do_out) {
        #pragma unroll
        for (int off = 1; off < 16; off <<= 1) {
            #pragma unroll
            for (int r = 0; r < 4; r++) {
                po[r][0] += __shfl_xor(po[r][0], off);
                po[r][1] += __shfl_xor(po[r][1], off);
                po[r][2] += __shfl_xor(po[r][2], off);
            }
        }
        if (l16 == 0) {
            #pragma unroll
            for (int r = 0; r < 4; r++) {
                int row = rbase + quad * 4 + r;
                out[(size_t)row * 3 + 0] = po[r][0] + bout[0];
                out[(size_t)row * 3 + 1] = po[r][1] + bout[1];
                out[(size_t)row * 3 + 2] = po[r][2] + bout[2];
            }
        }
    }
}

extern "C" void kernel_launch(void* const* d_in, const int* in_sizes, int n_in,
                              void* d_out, int out_size, void* d_ws, size_t ws_size,
                              hipStream_t stream) {
    const float* x     = (const float*)d_in[0];
    const int*   erow  = (const int*)  d_in[1];
    const int*   ecol  = (const int*)  d_in[2];
    const float* ew    = (const float*)d_in[3];
    const float* Win   = (const float*)d_in[4];
    const float* bin   = (const float*)d_in[5];
    const float* Wout  = (const float*)d_in[6];
    const float* bout  = (const float*)d_in[7];
    const float* Wconv = (const float*)d_in[8];
    float* out = (float*)d_out;

    char* ws = (char*)d_ws;
    const size_t NHb = (size_t)N_NODES * H * sizeof(unsigned short);  // 10,240,000
    unsigned short* xxbf  = (unsigned short*)(ws);
    unsigned short* x0bf  = (unsigned short*)(ws + NHb);
    unsigned short* hbf   = (unsigned short*)(ws + 2 * NHb);
    char* p = ws + 3 * NHb;
    unsigned short* Wtbf  = (unsigned short*)p;  p += 8 * H * H * 2;  // 262,144
    int*  cnt     = (int*) p;  p += 160256;                           // N ints, padded
    unsigned int* bucket = (unsigned int*)p;     // N * CAP * 4 = 15,360,000 B

    // zero bucket counters, then one mega-dispatch: scatter + W-fold + xin
    hipMemsetAsync(cnt, 0, (size_t)N_NODES * 4, stream);
    k_setup<<<SB_SCAT + SB_WPRE + SB_XIN, 256, 0, stream>>>(
        erow, ecol, ew, cnt, bucket, Wconv, Wtbf, x, Win, bin, x0bf, hbf);

    // try cooperative persistent kernel for all 8 layers; fall back to the
    // proven per-layer loop if the cooperative launch is rejected.
    void* args[] = { (void*)&cnt, (void*)&bucket, (void*)&x0bf, (void*)&hbf,
                     (void*)&xxbf, (void*)&Wtbf, (void*)&Wout, (void*)&bout,
                     (void*)&out };
    hipError_t err = hipLaunchCooperativeKernel((const void*)k_layers,
                                                dim3(PBLK), dim3(256),
                                                args, 0, stream);
    if (err != hipSuccess) {
        (void)hipGetLastError();   // clear sticky error state
        for (int l = 0; l < NLAYERS; l++) {
            k_spmm<<<N_NODES / 4,  256, 0, stream>>>(cnt, bucket, hbf, x0bf, xxbf);
            k_gemm<<<N_NODES / 32, 128, 0, stream>>>(xxbf, Wtbf + (size_t)l * H * H,
                                                     hbf, Wout, bout, out,
                                                     (l == NLAYERS - 1) ? 1 : 0);
        }
    }
}

// Round 19
// 460.065 us; speedup vs baseline: 3.3129x; 3.3129x over previous
//
#include <hip/hip_runtime.h>
#include <hip/hip_bf16.h>
#include <math.h>

#define N_NODES 40000
#define NE      640000
#define FIN     33
#define H       128
#define COUT    3
#define NLAYERS 8
#define ALPHA   0.1f
#define THETA   0.5f
#define CAP     96             // max bucket capacity; deg ~ Poisson(16), P(>96) ~ 1e-40

// setup mega-kernel block ranges
#define SB_SCAT 625            // scatter: 625 blocks * 256 thr * 4 edges = 640000
#define SB_WPRE 512            // wprep:   512 blocks * 256 = 131072 elements
#define SB_XIN  2500           // xin:     2500 blocks * 16 nodes = 40000

typedef __bf16 bf16x8 __attribute__((ext_vector_type(8)));
typedef float  f32x4  __attribute__((ext_vector_type(4)));

__device__ inline unsigned short f2bf(float f) {
    __hip_bfloat16 b = __float2bfloat16(f);
    return *(unsigned short*)&b;
}
__device__ inline float bf2f(unsigned short u) {
    __hip_bfloat16 b = *(__hip_bfloat16*)&u;
    return __bfloat162float(b);
}

// ---- setup mega-kernel: [scatter | wprep(W'-fold) | xin] by block range ----
__global__ __launch_bounds__(256) void k_setup(
        const int* __restrict__ row, const int* __restrict__ col,
        const float* __restrict__ w, int* __restrict__ cnt,
        unsigned int* __restrict__ bucket,
        const float* __restrict__ Wconv, unsigned short* __restrict__ Wtbf,
        const float* __restrict__ x, const float* __restrict__ Win,
        const float* __restrict__ bin,
        unsigned short* __restrict__ x0bf, unsigned short* __restrict__ hbf) {
    __shared__ float sW[H * FIN];
    __shared__ float sx[16][FIN];
    int b = blockIdx.x, t = threadIdx.x;

    if (b < SB_SCAT) {
        int e0 = (b * 256 + t) * 4;
        int r[4], pos[4];
        unsigned int rec[4];
        #pragma unroll
        for (int i = 0; i < 4; i++) {
            int e = e0 + i;
            r[i] = row[e];
            unsigned int wb = f2bf((1.0f - ALPHA) * w[e]);
            rec[i] = (wb << 16) | (unsigned int)col[e];
        }
        #pragma unroll
        for (int i = 0; i < 4; i++) pos[i] = atomicAdd(&cnt[r[i]], 1);
        #pragma unroll
        for (int i = 0; i < 4; i++) bucket[(size_t)r[i] * CAP + pos[i]] = rec[i];
        return;
    }
    if (b < SB_SCAT + SB_WPRE) {
        // W' = (1-beta)*I + beta*W, transposed to [l][j][k], bf16
        int idx = (b - SB_SCAT) * 256 + t;        // = l*16384 + k*128 + j
        int l = idx >> 14;
        int rem = idx & 16383;
        int k = rem >> 7, j = rem & 127;
        float beta = logf(THETA / (float)(l + 1) + 1.0f);
        float v = beta * Wconv[idx];
        if (j == k) v += 1.0f - beta;
        Wtbf[l * 16384 + j * 128 + k] = f2bf(v);
        return;
    }
    {
        // x0 = relu(x @ W_in^T + b_in); x0bf, hbf = bf16(x0)
        int n0 = (b - SB_SCAT - SB_WPRE) * 16;
        for (int i = t; i < H * FIN; i += 256) sW[i] = Win[i];
        for (int i = t; i < 16 * FIN; i += 256)
            sx[i / FIN][i % FIN] = x[(size_t)(n0 + i / FIN) * FIN + (i % FIN)];
        __syncthreads();
        int f = t % H;
        int l0 = t / H;
        float bv = bin[f];
        for (int lo = l0; lo < 16; lo += 2) {
            float acc = bv;
            #pragma unroll
            for (int k = 0; k < FIN; k++) acc += sx[lo][k] * sW[f * FIN + k];
            acc = fmaxf(acc, 0.f);
            size_t idx = (size_t)(n0 + lo) * H + f;
            unsigned short bb = f2bf(acc);
            x0bf[idx] = bb;
            hbf[idx] = bb;
        }
    }
}

// ---- xx = A@hbf + alpha*x0bf -> bf16; wave/row, lane-group gathers --------
// 16 lanes cover one 256B row via dwordx4 (16B/lane); 4 edges per load instr.
__global__ __launch_bounds__(256) void k_spmm(const int* __restrict__ cnt,
                       const unsigned int* __restrict__ bucket,
                       const unsigned short* __restrict__ hbf,
                       const unsigned short* __restrict__ x0bf,
                       unsigned short* __restrict__ xxbf) {
    int wave = (blockIdx.x * blockDim.x + threadIdx.x) >> 6;
    int lane = threadIdx.x & 63;
    if (wave >= N_NODES) return;
    int deg = cnt[wave];
    const unsigned int* ep = bucket + (size_t)wave * CAP;
    int slot = lane >> 4;              // 0..3: edge within a group of 4
    int fid  = lane & 15;              // feature block: features fid*8 .. +7

    float acc[8] = {0,0,0,0,0,0,0,0};

    for (int e = 0; e < deg; e += 16) {
        unsigned int u[4];
        uint4 q[4];
        #pragma unroll
        for (int k = 0; k < 4; k++) {
            int ei = e + k * 4 + slot;               // < CAP always (CAP%16==0)
            unsigned int uu = ep[ei];                // 16 lanes share address
            u[k] = (ei < deg) ? uu : 0u;
        }
        #pragma unroll
        for (int k = 0; k < 4; k++)
            q[k] = *(const uint4*)(hbf + (size_t)(u[k] & 0xffffu) * H + fid * 8);
        #pragma unroll
        for (int k = 0; k < 4; k++) {
            float w = bf2f((unsigned short)(u[k] >> 16));
            acc[0] += w * bf2f((unsigned short)(q[k].x & 0xffffu));
            acc[1] += w * bf2f((unsigned short)(q[k].x >> 16));
            acc[2] += w * bf2f((unsigned short)(q[k].y & 0xffffu));
            acc[3] += w * bf2f((unsigned short)(q[k].y >> 16));
            acc[4] += w * bf2f((unsigned short)(q[k].z & 0xffffu));
            acc[5] += w * bf2f((unsigned short)(q[k].z >> 16));
            acc[6] += w * bf2f((unsigned short)(q[k].w & 0xffffu));
            acc[7] += w * bf2f((unsigned short)(q[k].w >> 16));
        }
    }

    // reduce across the 4 slot-groups (lanes with equal fid)
    #pragma unroll
    for (int j = 0; j < 8; j++) {
        acc[j] += __shfl_xor(acc[j], 16);
        acc[j] += __shfl_xor(acc[j], 32);
    }

    if (slot == 0) {                    // lanes 0..15 hold the full row
        uint4 xq = *(const uint4*)(x0bf + (size_t)wave * H + fid * 8);
        float o0 = acc[0] + ALPHA * bf2f((unsigned short)(xq.x & 0xffffu));
        float o1 = acc[1] + ALPHA * bf2f((unsigned short)(xq.x >> 16));
        float o2 = acc[2] + ALPHA * bf2f((unsigned short)(xq.y & 0xffffu));
        float o3 = acc[3] + ALPHA * bf2f((unsigned short)(xq.y >> 16));
        float o4 = acc[4] + ALPHA * bf2f((unsigned short)(xq.z & 0xffffu));
        float o5 = acc[5] + ALPHA * bf2f((unsigned short)(xq.z >> 16));
        float o6 = acc[6] + ALPHA * bf2f((unsigned short)(xq.w & 0xffffu));
        float o7 = acc[7] + ALPHA * bf2f((unsigned short)(xq.w >> 16));
        uint4 r;
        r.x = (unsigned int)f2bf(o0) | ((unsigned int)f2bf(o1) << 16);
        r.y = (unsigned int)f2bf(o2) | ((unsigned int)f2bf(o3) << 16);
        r.z = (unsigned int)f2bf(o4) | ((unsigned int)f2bf(o5) << 16);
        r.w = (unsigned int)f2bf(o6) | ((unsigned int)f2bf(o7) << 16);
        *(uint4*)(xxbf + (size_t)wave * H + fid * 8) = r;
    }
}

// ---- MFMA GEMM + epilogue: hbf += relu(xx @ W')   (skip folded into W')
// block = 2 waves (128 thr), 32 rows; wave = 16 rows x 128 cols.
// do_out: also emit out = h @ W_out^T + b_out (last layer; fp32 hv in regs).
__global__ __launch_bounds__(128) void k_gemm(const unsigned short* __restrict__ xxbf,
                       const unsigned short* __restrict__ Wtbf,
                       unsigned short* __restrict__ hbf,
                       const float* __restrict__ Wout, const float* __restrict__ bout,
                       float* __restrict__ out, int do_out) {
    int t = threadIdx.x;
    int wv = t >> 6, lane = t & 63;
    int quad = lane >> 4, l16 = lane & 15;
    int rbase = blockIdx.x * 32 + wv * 16;

    f32x4 acc[8];
    #pragma unroll
    for (int j = 0; j < 8; j++) acc[j] = (f32x4){0.f, 0.f, 0.f, 0.f};

    #pragma unroll
    for (int k0 = 0; k0 < 4; k0++) {
        bf16x8 av = *(const bf16x8*)(xxbf + (size_t)(rbase + l16) * H + k0 * 32 + quad * 8);
        #pragma unroll
        for (int j = 0; j < 8; j++) {
            bf16x8 bv = *(const bf16x8*)(Wtbf + (size_t)(j * 16 + l16) * H + k0 * 32 + quad * 8);
            acc[j] = __builtin_amdgcn_mfma_f32_16x16x32_bf16(av, bv, acc[j], 0, 0, 0);
        }
    }

    float po[4][3];
    #pragma unroll
    for (int r = 0; r < 4; r++) { po[r][0] = 0.f; po[r][1] = 0.f; po[r][2] = 0.f; }

    #pragma unroll
    for (int j = 0; j < 8; j++) {
        int col = j * 16 + l16;
        float w0 = 0.f, w1 = 0.f, w2 = 0.f;
        if (do_out) { w0 = Wout[col]; w1 = Wout[H + col]; w2 = Wout[2 * H + col]; }
        #pragma unroll
        for (int r = 0; r < 4; r++) {
            int row = rbase + quad * 4 + r;        // C/D: row = quad*4 + reg
            size_t idx = (size_t)row * H + col;
            float hv = bf2f(hbf[idx]) + fmaxf(acc[j][r], 0.f);
            hbf[idx] = f2bf(hv);
            po[r][0] += hv * w0; po[r][1] += hv * w1; po[r][2] += hv * w2;
        }
    }

    if (do_out) {
        // reduce across the 16 lanes of each quad (xor strides stay in-quad)
        #pragma unroll
        for (int off = 1; off < 16; off <<= 1) {
            #pragma unroll
            for (int r = 0; r < 4; r++) {
                po[r][0] += __shfl_xor(po[r][0], off);
                po[r][1] += __shfl_xor(po[r][1], off);
                po[r][2] += __shfl_xor(po[r][2], off);
            }
        }
        if (l16 == 0) {
            #pragma unroll
            for (int r = 0; r < 4; r++) {
                int row = rbase + quad * 4 + r;
                out[(size_t)row * 3 + 0] = po[r][0] + bout[0];
                out[(size_t)row * 3 + 1] = po[r][1] + bout[1];
                out[(size_t)row * 3 + 2] = po[r][2] + bout[2];
            }
        }
    }
}

extern "C" void kernel_launch(void* const* d_in, const int* in_sizes, int n_in,
                              void* d_out, int out_size, void* d_ws, size_t ws_size,
                              hipStream_t stream) {
    const float* x     = (const float*)d_in[0];
    const int*   erow  = (const int*)  d_in[1];
    const int*   ecol  = (const int*)  d_in[2];
    const float* ew    = (const float*)d_in[3];
    const float* Win   = (const float*)d_in[4];
    const float* bin   = (const float*)d_in[5];
    const float* Wout  = (const float*)d_in[6];
    const float* bout  = (const float*)d_in[7];
    const float* Wconv = (const float*)d_in[8];
    float* out = (float*)d_out;

    char* ws = (char*)d_ws;
    const size_t NHb = (size_t)N_NODES * H * sizeof(unsigned short);  // 10,240,000
    unsigned short* xxbf  = (unsigned short*)(ws);
    unsigned short* x0bf  = (unsigned short*)(ws + NHb);
    unsigned short* hbf   = (unsigned short*)(ws + 2 * NHb);
    char* p = ws + 3 * NHb;
    unsigned short* Wtbf  = (unsigned short*)p;  p += 8 * H * H * 2;  // 262,144
    int*  cnt     = (int*) p;  p += 160256;                           // N ints, padded
    unsigned int* bucket = (unsigned int*)p;     // N * CAP * 4 = 15,360,000 B

    // zero bucket counters, then one mega-dispatch: scatter + W-fold + xin
    hipMemsetAsync(cnt, 0, (size_t)N_NODES * 4, stream);
    k_setup<<<SB_SCAT + SB_WPRE + SB_XIN, 256, 0, stream>>>(
        erow, ecol, ew, cnt, bucket, Wconv, Wtbf, x, Win, bin, x0bf, hbf);

    // layers: spmm -> xxbf (bf16); gemm: hbf += relu(xx@W') in place;
    // last layer's gemm also emits the output projection.
    for (int l = 0; l < NLAYERS; l++) {
        k_spmm<<<N_NODES / 4,  256, 0, stream>>>(cnt, bucket, hbf, x0bf, xxbf);
        k_gemm<<<N_NODES / 32, 128, 0, stream>>>(xxbf, Wtbf + (size_t)l * H * H,
                                                 hbf, Wout, bout, out,
                                                 (l == NLAYERS - 1) ? 1 : 0);
    }
}